// Round 8
// baseline (185.123 us; speedup 1.0000x reference)
//
#include <hip/hip_runtime.h>
#include <hip/hip_bf16.h>
#include <math.h>

typedef short s8 __attribute__((ext_vector_type(8)));   // 8 bf16 in 4 VGPRs
typedef float f4 __attribute__((ext_vector_type(4)));   // MFMA 16x16 acc
typedef unsigned short ushort_t;

__device__ __forceinline__ float fexp2f(float x) { return __builtin_amdgcn_exp2f(x); }
__device__ __forceinline__ float frcpf(float x)  { return __builtin_amdgcn_rcpf(x); }
__device__ __forceinline__ float sigf(float x) {
    return frcpf(1.f + fexp2f(x * -1.44269504f));
}
__device__ __forceinline__ float tanh_f(float x) {
    float e = fexp2f(x * 2.88539008f);
    return 1.f - 2.f * frcpf(e + 1.f);
}
__device__ __forceinline__ unsigned pk2(float a, float b) {
    __hip_bfloat162 r = __float22bfloat162_rn(make_float2(a, b));
    return *(unsigned*)&r;
}
__device__ __forceinline__ float b2f(ushort_t b) {
    return __uint_as_float(((unsigned)b) << 16);
}

// ---------------------------------------------------------------------------
// Convert Wih / Whh / SW^T to bf16 (weights only — emb conversion is fused
// into leafgru_mfma).
// ---------------------------------------------------------------------------
#define EMB_N   6400000          // 50000*128
#define W_N     49152            // 384*128
#define SW_N    16384            // 128*128
#define CVTW_N  (2 * W_N + SW_N)

__global__ __launch_bounds__(256) void cvtw_kernel(
    const float* __restrict__ wih, const float* __restrict__ whh,
    const float* __restrict__ sw,
    ushort_t* __restrict__ wihb, ushort_t* __restrict__ whhb,
    ushort_t* __restrict__ swtb)
{
    int i = (blockIdx.x * 256 + threadIdx.x) * 4;
    if (i >= CVTW_N) return;
    if (i < W_N) {
        float4 v = *(const float4*)(wih + i);
        uint2 o; o.x = pk2(v.x, v.y); o.y = pk2(v.z, v.w);
        *(uint2*)(wihb + i) = o;
    } else if (i < 2 * W_N) {
        int j = i - W_N;
        float4 v = *(const float4*)(whh + j);
        uint2 o; o.x = pk2(v.x, v.y); o.y = pk2(v.z, v.w);
        *(uint2*)(whhb + j) = o;
    } else {
        int j = i - 2 * W_N;
        int f = j >> 7, e0 = j & 127;
        uint2 o;
        o.x = pk2(sw[(e0 + 0) * 128 + f], sw[(e0 + 1) * 128 + f]);
        o.y = pk2(sw[(e0 + 2) * 128 + f], sw[(e0 + 3) * 128 + f]);
        *(uint2*)(swtb + j) = o;         // SWt[f][e]
    }
}

// ---------------------------------------------------------------------------
// Leaf GRU + leaf attention SCORE, both pure functions of the token:
// computed ONCE per vocab entry (50176 padded rows). NOW ALSO converts the
// fp32 emb table to bf16 inline (writes embb as a side effect, bit-identical
// pk2) — deletes the separate 25.6MB-read emb-cvt pass.
// ---------------------------------------------------------------------------
__global__ __launch_bounds__(512, 2) void leafgru_mfma(
    const float* __restrict__ emb, const ushort_t* __restrict__ wihb,
    const float* __restrict__ bih, const float* __restrict__ bhh,
    const ushort_t* __restrict__ swt, const float* __restrict__ sb,
    const float* __restrict__ cw,
    ushort_t* __restrict__ embb,
    ushort_t* __restrict__ hleaf, float* __restrict__ sleaf)
{
    __shared__ ushort_t xs[128 * 136];
    __shared__ ushort_t hnew[128 * 136];
    __shared__ float scp[8][128];

    const int t = threadIdx.x;
    const int base = blockIdx.x * 128;       // vocab row base

    {
        int lr = t >> 2, c0 = (t & 3) * 32;
        int row = base + lr;
        int srow = min(row, 49999);          // clamp pad rows (no OOB on emb)
        const float* src = emb + (size_t)srow * 128 + c0;
        ushort_t* dst = &xs[lr * 136 + c0];
        #pragma unroll
        for (int i = 0; i < 4; ++i) {
            float4 a = *(const float4*)(src + 8 * i);
            float4 b = *(const float4*)(src + 8 * i + 4);
            uint4 o;
            o.x = pk2(a.x, a.y); o.y = pk2(a.z, a.w);
            o.z = pk2(b.x, b.y); o.w = pk2(b.z, b.w);
            *(uint4*)(dst + 8 * i) = o;
            if (row < 50000)
                *(uint4*)(embb + (size_t)row * 128 + c0 + 8 * i) = o;
        }
    }

    const int lane = t & 63, w = t >> 6;
    const int quad = lane >> 4, l15 = lane & 15;
    const int gA = w * 16 + l15;
    const int g0 = w * 16 + quad * 4;

    s8 bwi[3][4];
    #pragma unroll
    for (int gm = 0; gm < 3; ++gm) {
        const ushort_t* wp = wihb + (size_t)(gm * 128 + gA) * 128 + quad * 8;
        #pragma unroll
        for (int s = 0; s < 4; ++s) bwi[gm][s] = *(const s8*)(wp + 32 * s);
    }
    float bR[4], bZ[4], biN[4], bhN[4];
    {
        float4 a = *(const float4*)(bih + g0);
        float4 b = *(const float4*)(bhh + g0);
        bR[0] = a.x + b.x; bR[1] = a.y + b.y; bR[2] = a.z + b.z; bR[3] = a.w + b.w;
        float4 c = *(const float4*)(bih + 128 + g0);
        float4 d = *(const float4*)(bhh + 128 + g0);
        bZ[0] = c.x + d.x; bZ[1] = c.y + d.y; bZ[2] = c.z + d.z; bZ[3] = c.w + d.w;
        float4 e = *(const float4*)(bih + 256 + g0);
        float4 f = *(const float4*)(bhh + 256 + g0);
        biN[0] = e.x; biN[1] = e.y; biN[2] = e.z; biN[3] = e.w;
        bhN[0] = f.x; bhN[1] = f.y; bhN[2] = f.z; bhN[3] = f.w;
    }

    __syncthreads();

    #pragma unroll 1
    for (int mt = 0; mt < 8; ++mt) {
        const int row = mt * 16 + l15;
        s8 ax[4];
        const ushort_t* ap = &xs[row * 136 + quad * 8];
        #pragma unroll
        for (int s = 0; s < 4; ++s) ax[s] = *(const s8*)(ap + 32 * s);

        f4 accR = (f4)0.f, accZ = (f4)0.f, accN = (f4)0.f;
        #pragma unroll
        for (int s = 0; s < 4; ++s) {
            accR = __builtin_amdgcn_mfma_f32_16x16x32_bf16(bwi[0][s], ax[s], accR, 0, 0, 0);
            accZ = __builtin_amdgcn_mfma_f32_16x16x32_bf16(bwi[1][s], ax[s], accZ, 0, 0, 0);
            accN = __builtin_amdgcn_mfma_f32_16x16x32_bf16(bwi[2][s], ax[s], accN, 0, 0, 0);
        }
        float hv[4];
        #pragma unroll
        for (int r = 0; r < 4; ++r) {
            // leaf GRU (h0=0), 5 transcendentals:
            // h = tanh(an)*(1-sig(aZ)) = (E-1)*F / ((E+1)*(1+F))
            float G = fexp2f((accR[r] + bR[r]) * -1.44269504f);
            float rr = frcpf(1.f + G);
            float an = accN[r] + biN[r] + rr * bhN[r];
            float E = fexp2f(an * 2.88539008f);
            float F = fexp2f((accZ[r] + bZ[r]) * -1.44269504f);
            float d = frcpf((E + 1.f) * (1.f + F));
            hv[r] = (E - 1.f) * F * d;
        }
        uint2 ov; ov.x = pk2(hv[0], hv[1]); ov.y = pk2(hv[2], hv[3]);
        *(uint2*)&hnew[row * 136 + g0] = ov;
        *(uint2*)(hleaf + (size_t)(base + row) * 128 + g0) = ov;
    }
    __syncthreads();

    // ---- attention score per vocab row ----
    s8 bsw[4];
    {
        const ushort_t* wp = swt + (size_t)gA * 128 + quad * 8;
        #pragma unroll
        for (int s = 0; s < 4; ++s) bsw[s] = *(const s8*)(wp + 32 * s);
    }
    float sb4[4], cw4[4];
    {
        float4 a = *(const float4*)(sb + g0);
        float4 b = *(const float4*)(cw + g0);
        sb4[0] = a.x; sb4[1] = a.y; sb4[2] = a.z; sb4[3] = a.w;
        cw4[0] = b.x; cw4[1] = b.y; cw4[2] = b.z; cw4[3] = b.w;
    }

    #pragma unroll 1
    for (int mt = 0; mt < 8; ++mt) {
        const int crow = mt * 16 + l15;
        s8 a[4];
        const ushort_t* ap = &hnew[crow * 136 + quad * 8];
        #pragma unroll
        for (int s = 0; s < 4; ++s) a[s] = *(const s8*)(ap + 32 * s);

        f4 acc = (f4)0.f;
        #pragma unroll
        for (int s = 0; s < 4; ++s)
            acc = __builtin_amdgcn_mfma_f32_16x16x32_bf16(bsw[s], a[s], acc, 0, 0, 0);

        float part = 0.f;
        #pragma unroll
        for (int r = 0; r < 4; ++r)
            part += tanh_f(acc[r] + sb4[r]) * cw4[r];
        part += __shfl_xor(part, 16);
        part += __shfl_xor(part, 32);
        if (quad == 0) scp[w][crow] = part;
    }
    __syncthreads();

    if (t < 128) {
        float s = 0.f;
        #pragma unroll
        for (int ww = 0; ww < 8; ++ww) s += scp[ww][t];
        sleaf[base + t] = tanh_f(s);
    }
}

// ---------------------------------------------------------------------------
// MERGED L4 kernel: leaf-blend h0 (pipelined quarters) + GRU MFMA + L4
// attention + sibling-max, all in one block. Block = (L3 parent p, 32-batch
// tile): 128 rows = 4 sibling L4 nodes x 32 batch. Quarter q == sibling node
// 4p+q. After quarter q's MFMA the GRU output h is written back into the
// DEAD xs rows (held in regs across the barrier); attnmax runs in-place.
// ---------------------------------------------------------------------------
__global__ __launch_bounds__(512, 2) void gru_attn_l4(
    const int* __restrict__ tokens, const ushort_t* __restrict__ embb,
    const ushort_t* __restrict__ hleaf, const float* __restrict__ sleaf,
    const ushort_t* __restrict__ wihb, const ushort_t* __restrict__ whhb,
    const float* __restrict__ bih, const float* __restrict__ bhh,
    const ushort_t* __restrict__ swt, const float* __restrict__ sb,
    const float* __restrict__ cw,
    ushort_t* __restrict__ h0out, ushort_t* __restrict__ pmaxs)
{
    __shared__ ushort_t xs[128 * 136];     // emb x -> (after GRU) h
    __shared__ ushort_t hs[128 * 136];     // h0 (leaf-attn blend)
    __shared__ float scp[8][128];
    __shared__ float sc[128];
    __shared__ float al[4][32];

    const int t = threadIdx.x;
    const int p  = blockIdx.x >> 3;          // L3 parent 0..63
    const int b0 = (blockIdx.x & 7) * 32;    // batch tile

    const int lane = t & 63, w = t >> 6;
    const int quad = lane >> 4, l15 = lane & 15;
    const int gA = w * 16 + l15;
    const int g0 = w * 16 + quad * 4;

    // staging geometry: 16 thr/row, 16 B (8 shorts) per thread
    const int slr = t >> 4;                  // row-in-quarter 0..31
    const int sc0 = (t & 15) * 8;            // col offset (shorts)

    // ---- weights & biases ----
    s8 bwi[3][4], bwh[3][4];
    #pragma unroll
    for (int gm = 0; gm < 3; ++gm) {
        const ushort_t* wp = wihb + (size_t)(gm * 128 + gA) * 128 + quad * 8;
        #pragma unroll
        for (int s = 0; s < 4; ++s) bwi[gm][s] = *(const s8*)(wp + 32 * s);
        const ushort_t* wp2 = whhb + (size_t)(gm * 128 + gA) * 128 + quad * 8;
        #pragma unroll
        for (int s = 0; s < 4; ++s) bwh[gm][s] = *(const s8*)(wp2 + 32 * s);
    }
    float bR[4], bZ[4], biN[4], bhN[4];
    {
        float4 a = *(const float4*)(bih + g0);
        float4 b = *(const float4*)(bhh + g0);
        bR[0] = a.x + b.x; bR[1] = a.y + b.y; bR[2] = a.z + b.z; bR[3] = a.w + b.w;
        float4 c = *(const float4*)(bih + 128 + g0);
        float4 d = *(const float4*)(bhh + 128 + g0);
        bZ[0] = c.x + d.x; bZ[1] = c.y + d.y; bZ[2] = c.z + d.z; bZ[3] = c.w + d.w;
        float4 e = *(const float4*)(bih + 256 + g0);
        float4 f = *(const float4*)(bhh + 256 + g0);
        biN[0] = e.x; biN[1] = e.y; biN[2] = e.z; biN[3] = e.w;
        bhN[0] = f.x; bhN[1] = f.y; bhN[2] = f.z; bhN[3] = f.w;
    }

    // ---- pipeline registers for the staged quarter ----
    s8 pv0, pv1, pv2, pv3, pxv;
    float ps0, ps1, ps2, ps3;
    int pnode, pb;

#define STAGE_LOAD(Q) {                                                     \
        int lr_ = (Q) * 32 + slr;                                           \
        pnode = 4 * p + (lr_ >> 5); pb = b0 + (lr_ & 31);                   \
        int lt0 = tokens[(341 + 4 * pnode + 0) * 256 + pb];                 \
        int lt1 = tokens[(341 + 4 * pnode + 1) * 256 + pb];                 \
        int lt2 = tokens[(341 + 4 * pnode + 2) * 256 + pb];                 \
        int lt3 = tokens[(341 + 4 * pnode + 3) * 256 + pb];                 \
        pv0 = *(const s8*)(hleaf + (size_t)lt0 * 128 + sc0);                \
        pv1 = *(const s8*)(hleaf + (size_t)lt1 * 128 + sc0);                \
        pv2 = *(const s8*)(hleaf + (size_t)lt2 * 128 + sc0);                \
        pv3 = *(const s8*)(hleaf + (size_t)lt3 * 128 + sc0);                \
        ps0 = sleaf[lt0]; ps1 = sleaf[lt1]; ps2 = sleaf[lt2]; ps3 = sleaf[lt3]; \
        int tok_ = tokens[(85 + pnode) * 256 + pb];                         \
        pxv = *(const s8*)(embb + (size_t)tok_ * 128 + sc0);                \
    }

#define STAGE_FIN(Q) {                                                      \
        int lr_ = (Q) * 32 + slr;                                           \
        float m_ = fmaxf(fmaxf(ps0, ps1), fmaxf(ps2, ps3));                 \
        float e0_ = fexp2f((ps0 - m_) * 1.44269504f);                       \
        float e1_ = fexp2f((ps1 - m_) * 1.44269504f);                       \
        float e2_ = fexp2f((ps2 - m_) * 1.44269504f);                       \
        float e3_ = fexp2f((ps3 - m_) * 1.44269504f);                       \
        float inv_ = frcpf(e0_ + e1_ + e2_ + e3_);                          \
        float a0_ = e0_ * inv_, a1_ = e1_ * inv_;                           \
        float a2_ = e2_ * inv_, a3_ = e3_ * inv_;                           \
        float o_[8], mm_[8];                                                \
        _Pragma("unroll")                                                   \
        for (int j = 0; j < 8; ++j) {                                       \
            float y0 = b2f((ushort_t)pv0[j]), y1 = b2f((ushort_t)pv1[j]);   \
            float y2 = b2f((ushort_t)pv2[j]), y3 = b2f((ushort_t)pv3[j]);   \
            o_[j]  = a0_ * y0 + a1_ * y1 + a2_ * y2 + a3_ * y3;             \
            mm_[j] = fmaxf(fmaxf(y0, y1), fmaxf(y2, y3));                   \
        }                                                                   \
        uint4 ovv_, mvv_;                                                   \
        ovv_.x = pk2(o_[0], o_[1]);  ovv_.y = pk2(o_[2], o_[3]);            \
        ovv_.z = pk2(o_[4], o_[5]);  ovv_.w = pk2(o_[6], o_[7]);            \
        mvv_.x = pk2(mm_[0], mm_[1]); mvv_.y = pk2(mm_[2], mm_[3]);         \
        mvv_.z = pk2(mm_[4], mm_[5]); mvv_.w = pk2(mm_[6], mm_[7]);         \
        *(uint4*)&hs[lr_ * 136 + sc0] = ovv_;                               \
        *(s8*)&xs[lr_ * 136 + sc0] = pxv;                                   \
        *(uint4*)(pmaxs + ((size_t)pb * 320 + pnode) * 128 + sc0) = mvv_;   \
    }

    // ---- prologue: stage quarter 0 ----
    STAGE_LOAD(0);
    STAGE_FIN(0);
    __syncthreads();

    uint2 ph[2];                            // h output held across barrier

    #pragma unroll 1
    for (int q = 0; q < 4; ++q) {
        if (q < 3) STAGE_LOAD(q + 1);      // issue next quarter's gathers

        // ---- MFMA for quarter q: rows q*32 .. q*32+31 (mt = 2q, 2q+1) ----
        #pragma unroll 1
        for (int mq = 0; mq < 2; ++mq) {
            const int mt = q * 2 + mq;
            const int row = mt * 16 + l15;
            s8 ax[4], ah[4];
            {
                const ushort_t* ap = &xs[row * 136 + quad * 8];
                #pragma unroll
                for (int s = 0; s < 4; ++s) ax[s] = *(const s8*)(ap + 32 * s);
                const ushort_t* hp = &hs[row * 136 + quad * 8];
                #pragma unroll
                for (int s = 0; s < 4; ++s) ah[s] = *(const s8*)(hp + 32 * s);
            }

            f4 accR = (f4)0.f, accZ = (f4)0.f, accN = (f4)0.f, accNh = (f4)0.f;
            #pragma unroll
            for (int s = 0; s < 4; ++s) {
                accR = __builtin_amdgcn_mfma_f32_16x16x32_bf16(bwi[0][s], ax[s], accR, 0, 0, 0);
                accZ = __builtin_amdgcn_mfma_f32_16x16x32_bf16(bwi[1][s], ax[s], accZ, 0, 0, 0);
                accN = __builtin_amdgcn_mfma_f32_16x16x32_bf16(bwi[2][s], ax[s], accN, 0, 0, 0);
            }
            #pragma unroll
            for (int s = 0; s < 4; ++s) {
                accR  = __builtin_amdgcn_mfma_f32_16x16x32_bf16(bwh[0][s], ah[s], accR, 0, 0, 0);
                accZ  = __builtin_amdgcn_mfma_f32_16x16x32_bf16(bwh[1][s], ah[s], accZ, 0, 0, 0);
                accNh = __builtin_amdgcn_mfma_f32_16x16x32_bf16(bwh[2][s], ah[s], accNh, 0, 0, 0);
            }

            float h0v[4];
            {
                short4 h04 = *(const short4*)&hs[row * 136 + g0];
                h0v[0] = b2f((ushort_t)h04.x); h0v[1] = b2f((ushort_t)h04.y);
                h0v[2] = b2f((ushort_t)h04.z); h0v[3] = b2f((ushort_t)h04.w);
            }
            float hv[4];
            #pragma unroll
            for (int r = 0; r < 4; ++r) {
                // h = (nn*(1-z) + z*h0) = ((E-1)*F + h0*(E+1)) / ((E+1)*(1+F))
                float G = fexp2f((accR[r] + bR[r]) * -1.44269504f);
                float rr = frcpf(1.f + G);
                float an = accN[r] + biN[r] + rr * (accNh[r] + bhN[r]);
                float E = fexp2f(an * 2.88539008f);
                float F = fexp2f((accZ[r] + bZ[r]) * -1.44269504f);
                float d = frcpf((E + 1.f) * (1.f + F));
                hv[r] = ((E - 1.f) * F + h0v[r] * (E + 1.f)) * d;
            }
            uint2 ov; ov.x = pk2(hv[0], hv[1]); ov.y = pk2(hv[2], hv[3]);
            ph[mq] = ov;
        }

        if (q < 3) STAGE_FIN(q + 1);       // wait gathers, blend, LDS write
        __syncthreads();

        // ---- write quarter q's h into its now-dead xs rows ----
        #pragma unroll
        for (int mq = 0; mq < 2; ++mq) {
            const int row = (q * 2 + mq) * 16 + l15;
            *(uint2*)&xs[row * 136 + g0] = ph[mq];
        }
    }
#undef STAGE_LOAD
#undef STAGE_FIN

    __syncthreads();                        // all h rows visible in xs

    // ================= L4 attention + sibling max (in-place) =================
    s8 bsw[4];
    {
        const ushort_t* wp = swt + (size_t)gA * 128 + quad * 8;
        #pragma unroll
        for (int s = 0; s < 4; ++s) bsw[s] = *(const s8*)(wp + 32 * s);
    }
    float sb4[4], cw4[4];
    {
        float4 a = *(const float4*)(sb + g0);
        float4 b = *(const float4*)(cw + g0);
        sb4[0] = a.x; sb4[1] = a.y; sb4[2] = a.z; sb4[3] = a.w;
        cw4[0] = b.x; cw4[1] = b.y; cw4[2] = b.z; cw4[3] = b.w;
    }

    #pragma unroll 1
    for (int mt = 0; mt < 8; ++mt) {
        const int crow = mt * 16 + l15;
        s8 a[4];
        const ushort_t* ap = &xs[crow * 136 + quad * 8];
        #pragma unroll
        for (int s = 0; s < 4; ++s) a[s] = *(const s8*)(ap + 32 * s);

        f4 acc = (f4)0.f;
        #pragma unroll
        for (int s = 0; s < 4; ++s)
            acc = __builtin_amdgcn_mfma_f32_16x16x32_bf16(bsw[s], a[s], acc, 0, 0, 0);

        float part = 0.f;
        #pragma unroll
        for (int r = 0; r < 4; ++r)
            part += tanh_f(acc[r] + sb4[r]) * cw4[r];
        part += __shfl_xor(part, 16);
        part += __shfl_xor(part, 32);
        if (quad == 0) scp[w][crow] = part;
    }
    __syncthreads();

    if (t < 128) {
        float s = 0.f;
        #pragma unroll
        for (int ww = 0; ww < 8; ++ww) s += scp[ww][t];
        sc[t] = tanh_f(s);
    }
    __syncthreads();

    if (t < 32) {
        float s0 = sc[t], s1 = sc[32 + t], s2 = sc[64 + t], s3 = sc[96 + t];
        float m = fmaxf(fmaxf(s0, s1), fmaxf(s2, s3));
        float e0 = fexp2f((s0 - m) * 1.44269504f), e1 = fexp2f((s1 - m) * 1.44269504f);
        float e2 = fexp2f((s2 - m) * 1.44269504f), e3 = fexp2f((s3 - m) * 1.44269504f);
        float inv = frcpf(e0 + e1 + e2 + e3);
        al[0][t] = e0 * inv; al[1][t] = e1 * inv; al[2][t] = e2 * inv; al[3][t] = e3 * inv;
    }
    __syncthreads();

    {
        int bl = t >> 4, e0 = (t & 15) * 8;
        float a0 = al[0][bl], a1 = al[1][bl], a2 = al[2][bl], a3 = al[3][bl];
        s8 c0v = *(const s8*)&xs[(0 * 32 + bl) * 136 + e0];
        s8 c1v = *(const s8*)&xs[(1 * 32 + bl) * 136 + e0];
        s8 c2v = *(const s8*)&xs[(2 * 32 + bl) * 136 + e0];
        s8 c3v = *(const s8*)&xs[(3 * 32 + bl) * 136 + e0];
        float o[8], m[8];
        #pragma unroll
        for (int j = 0; j < 8; ++j) {
            float x0 = b2f((ushort_t)c0v[j]), x1 = b2f((ushort_t)c1v[j]);
            float x2 = b2f((ushort_t)c2v[j]), x3 = b2f((ushort_t)c3v[j]);
            o[j] = a0 * x0 + a1 * x1 + a2 * x2 + a3 * x3;
            m[j] = fmaxf(fmaxf(x0, x1), fmaxf(x2, x3));
        }
        uint4 ovv, mvv;
        ovv.x = pk2(o[0], o[1]); ovv.y = pk2(o[2], o[3]);
        ovv.z = pk2(o[4], o[5]); ovv.w = pk2(o[6], o[7]);
        mvv.x = pk2(m[0], m[1]); mvv.y = pk2(m[2], m[3]);
        mvv.z = pk2(m[4], m[5]); mvv.w = pk2(m[6], m[7]);
        // h0_3: [node][batch][col]
        size_t rh = ((size_t)p * 256 + b0 + bl) * 128 + e0;
        *(uint4*)(h0out + rh) = ovv;
        // pmax: [batch][slot][col], L4 slots start at 256
        size_t rp = ((size_t)(b0 + bl) * 320 + 256 + p) * 128 + e0;
        *(uint4*)(pmaxs + rp) = mvv;
    }
}

// ---------------------------------------------------------------------------
// TAIL kernel: L3/L2/L1/root + final max. 256 blocks x 1 batch column.
// ---------------------------------------------------------------------------
__global__ __launch_bounds__(512, 1) void tail_kernel(
    const int* __restrict__ tokens, const ushort_t* __restrict__ embb,
    const ushort_t* __restrict__ wihb, const ushort_t* __restrict__ whhb,
    const float* __restrict__ bih, const float* __restrict__ bhh,
    const ushort_t* __restrict__ swt, const float* __restrict__ sb,
    const float* __restrict__ cw,
    const ushort_t* __restrict__ h0g,      // h0 for L3 (64 nodes, [n][b][c])
    const ushort_t* __restrict__ pmax,     // [batch][320][128]
    float* __restrict__ out)
{
    __shared__ ushort_t xs[64 * 136];
    __shared__ ushort_t hnew[64 * 136];
    __shared__ ushort_t hs[64 * 136];      // h0: staged (L3), attn-written after
    __shared__ float scp[8][64];
    __shared__ float sc[64];
    __shared__ float al[4][16];
    __shared__ float smax[4][128];
    __shared__ float wpart[8][128];

    const int t = threadIdx.x;
    const int bb = blockIdx.x;             // one batch column
    const int lane = t & 63, w = t >> 6;
    const int quad = lane >> 4, l15 = lane & 15;
    const int gA = w * 16 + l15;
    const int g0 = w * 16 + quad * 4;

    s8 bwi[3][4], bwh[3][4];
    #pragma unroll
    for (int gm = 0; gm < 3; ++gm) {
        const ushort_t* wp = wihb + (size_t)(gm * 128 + gA) * 128 + quad * 8;
        #pragma unroll
        for (int s = 0; s < 4; ++s) bwi[gm][s] = *(const s8*)(wp + 32 * s);
        const ushort_t* wp2 = whhb + (size_t)(gm * 128 + gA) * 128 + quad * 8;
        #pragma unroll
        for (int s = 0; s < 4; ++s) bwh[gm][s] = *(const s8*)(wp2 + 32 * s);
    }
    float bR[4], bZ[4], biN[4], bhN[4];
    {
        float4 a = *(const float4*)(bih + g0);
        float4 b = *(const float4*)(bhh + g0);
        bR[0] = a.x + b.x; bR[1] = a.y + b.y; bR[2] = a.z + b.z; bR[3] = a.w + b.w;
        float4 c = *(const float4*)(bih + 128 + g0);
        float4 d = *(const float4*)(bhh + 128 + g0);
        bZ[0] = c.x + d.x; bZ[1] = c.y + d.y; bZ[2] = c.z + d.z; bZ[3] = c.w + d.w;
        float4 e = *(const float4*)(bih + 256 + g0);
        float4 f = *(const float4*)(bhh + 256 + g0);
        biN[0] = e.x; biN[1] = e.y; biN[2] = e.z; biN[3] = e.w;
        bhN[0] = f.x; bhN[1] = f.y; bhN[2] = f.z; bhN[3] = f.w;
    }
    s8 bsw[4];
    {
        const ushort_t* wp = swt + (size_t)gA * 128 + quad * 8;
        #pragma unroll
        for (int s = 0; s < 4; ++s) bsw[s] = *(const s8*)(wp + 32 * s);
    }
    float sb4[4], cw4[4];
    {
        float4 a = *(const float4*)(sb + g0);
        float4 b = *(const float4*)(cw + g0);
        sb4[0] = a.x; sb4[1] = a.y; sb4[2] = a.z; sb4[3] = a.w;
        cw4[0] = b.x; cw4[1] = b.y; cw4[2] = b.z; cw4[3] = b.w;
    }

    float vmax = -INFINITY;

    const int nodesA[4] = {64, 16, 4, 1};
    const int tok0A[4]  = {21, 5, 1, 0};

    #pragma unroll 1
    for (int L = 0; L < 4; ++L) {
        const int nodes = nodesA[L], tok0 = tok0A[L];
        const int R = (nodes < 16) ? 16 : nodes;   // 64,16,16,16
        const int mts = R >> 4;

        // ---- stage x (+h0 from global for L3): 8 thr/row, 16 shorts ----
        {
            int lr = t >> 3, c0 = (t & 7) * 16;
            if (lr < R) {
                int n = min(lr, nodes - 1);        // clamp -> dup pad rows
                int tok = tokens[(tok0 + n) * 256 + bb];
                const ushort_t* src = embb + (size_t)tok * 128 + c0;
                ushort_t* dst = &xs[lr * 136 + c0];
                *(s8*)(dst)     = *(const s8*)(src);
                *(s8*)(dst + 8) = *(const s8*)(src + 8);
                if (L == 0) {
                    const ushort_t* hsrc = h0g + ((size_t)n * 256 + bb) * 128 + c0;
                    ushort_t* hdst = &hs[lr * 136 + c0];
                    *(s8*)(hdst)     = *(const s8*)(hsrc);
                    *(s8*)(hdst + 8) = *(const s8*)(hsrc + 8);
                }
            }
        }
        __syncthreads();

        // ---- GRU ----
        for (int mt = 0; mt < mts; ++mt) {
            const int row = mt * 16 + l15;
            const int hr = min(row, nodes - 1);    // clamped h0 row
            s8 ax[4], ah[4];
            {
                const ushort_t* ap = &xs[row * 136 + quad * 8];
                #pragma unroll
                for (int s = 0; s < 4; ++s) ax[s] = *(const s8*)(ap + 32 * s);
                const ushort_t* hp = &hs[hr * 136 + quad * 8];
                #pragma unroll
                for (int s = 0; s < 4; ++s) ah[s] = *(const s8*)(hp + 32 * s);
            }
            f4 accR = (f4)0.f, accZ = (f4)0.f, accN = (f4)0.f, accNh = (f4)0.f;
            #pragma unroll
            for (int s = 0; s < 4; ++s) {
                accR = __builtin_amdgcn_mfma_f32_16x16x32_bf16(bwi[0][s], ax[s], accR, 0, 0, 0);
                accZ = __builtin_amdgcn_mfma_f32_16x16x32_bf16(bwi[1][s], ax[s], accZ, 0, 0, 0);
                accN = __builtin_amdgcn_mfma_f32_16x16x32_bf16(bwi[2][s], ax[s], accN, 0, 0, 0);
            }
            #pragma unroll
            for (int s = 0; s < 4; ++s) {
                accR  = __builtin_amdgcn_mfma_f32_16x16x32_bf16(bwh[0][s], ah[s], accR, 0, 0, 0);
                accZ  = __builtin_amdgcn_mfma_f32_16x16x32_bf16(bwh[1][s], ah[s], accZ, 0, 0, 0);
                accNh = __builtin_amdgcn_mfma_f32_16x16x32_bf16(bwh[2][s], ah[s], accNh, 0, 0, 0);
            }
            float h0v[4];
            {
                short4 h04 = *(const short4*)&hs[hr * 136 + g0];
                h0v[0] = b2f((ushort_t)h04.x); h0v[1] = b2f((ushort_t)h04.y);
                h0v[2] = b2f((ushort_t)h04.z); h0v[3] = b2f((ushort_t)h04.w);
            }
            float hv[4];
            #pragma unroll
            for (int r = 0; r < 4; ++r) {
                float rr = sigf(accR[r] + bR[r]);
                float zz = sigf(accZ[r] + bZ[r]);
                float nn = tanh_f(accN[r] + biN[r] + rr * (accNh[r] + bhN[r]));
                hv[r] = nn + zz * (h0v[r] - nn);
            }
            uint2 ov; ov.x = pk2(hv[0], hv[1]); ov.y = pk2(hv[2], hv[3]);
            *(uint2*)&hnew[row * 136 + g0] = ov;
        }
        __syncthreads();

        // ---- running max (pad rows are dups of real rows -> harmless) ----
        {
            int col = t & 127, g = t >> 7;
            for (int r = g; r < R; r += 4)
                vmax = fmaxf(vmax, b2f(hnew[r * 136 + col]));
        }

        if (L < 3) {
            // ---- attention scores ----
            for (int mt = 0; mt < mts; ++mt) {
                const int crow = mt * 16 + l15;
                s8 a[4];
                const ushort_t* ap = &hnew[crow * 136 + quad * 8];
                #pragma unroll
                for (int s = 0; s < 4; ++s) a[s] = *(const s8*)(ap + 32 * s);
                f4 acc = (f4)0.f;
                #pragma unroll
                for (int s = 0; s < 4; ++s)
                    acc = __builtin_amdgcn_mfma_f32_16x16x32_bf16(bsw[s], a[s], acc, 0, 0, 0);
                float part = 0.f;
                #pragma unroll
                for (int r = 0; r < 4; ++r)
                    part += tanh_f(acc[r] + sb4[r]) * cw4[r];
                part += __shfl_xor(part, 16);
                part += __shfl_xor(part, 32);
                if (quad == 0) scp[w][crow] = part;
            }
            __syncthreads();
            if (t < R) {
                float s = 0.f;
                #pragma unroll
                for (int g = 0; g < 8; ++g) s += scp[g][t];
                sc[t] = tanh_f(s);
            }
            __syncthreads();
            const int P = nodes >> 2;              // parents: 16, 4, 1
            if (t < P) {
                float s0 = sc[4 * t + 0], s1 = sc[4 * t + 1];
                float s2 = sc[4 * t + 2], s3 = sc[4 * t + 3];
                float m = fmaxf(fmaxf(s0, s1), fmaxf(s2, s3));
                float e0 = fexp2f((s0 - m) * 1.44269504f);
                float e1 = fexp2f((s1 - m) * 1.44269504f);
                float e2 = fexp2f((s2 - m) * 1.44269504f);
                float e3 = fexp2f((s3 - m) * 1.44269504f);
                float inv = frcpf(e0 + e1 + e2 + e3);
                al[0][t] = e0 * inv; al[1][t] = e1 * inv;
                al[2][t] = e2 * inv; al[3][t] = e3 * inv;
            }
            __syncthreads();
            if (t < 16 * P) {
                int bl = t >> 4, e0 = (t & 15) * 8;
                float a0 = al[0][bl], a1 = al[1][bl], a2 = al[2][bl], a3 = al[3][bl];
                s8 c0v = *(const s8*)&hnew[(4 * bl + 0) * 136 + e0];
                s8 c1v = *(const s8*)&hnew[(4 * bl + 1) * 136 + e0];
                s8 c2v = *(const s8*)&hnew[(4 * bl + 2) * 136 + e0];
                s8 c3v = *(const s8*)&hnew[(4 * bl + 3) * 136 + e0];
                float o[8];
                #pragma unroll
                for (int j = 0; j < 8; ++j) {
                    o[j] = a0 * b2f((ushort_t)c0v[j]) + a1 * b2f((ushort_t)c1v[j])
                         + a2 * b2f((ushort_t)c2v[j]) + a3 * b2f((ushort_t)c3v[j]);
                }
                uint4 ovv;
                ovv.x = pk2(o[0], o[1]); ovv.y = pk2(o[2], o[3]);
                ovv.z = pk2(o[4], o[5]); ovv.w = pk2(o[6], o[7]);
                *(uint4*)&hs[bl * 136 + e0] = ovv;   // parent h0 -> hs row bl
            }
            __syncthreads();
        }
    }

    // ---- own-level max -> LDS ----
    smax[t >> 7][t & 127] = vmax;

    // ---- final reduce over 320 pmax slots (contiguous per batch row) ----
    {
        int cg = t & 15;              // col group (8 cols) == lane & 15
        int ck = t >> 4;              // slot chunk 0..31
        const ushort_t* base = pmax + (size_t)bb * 320 * 128 + cg * 8;
        float v8[8];
        #pragma unroll
        for (int j = 0; j < 8; ++j) v8[j] = -INFINITY;
        for (int s = ck; s < 320; s += 32) {
            s8 c = *(const s8*)(base + (size_t)s * 128);
            #pragma unroll
            for (int j = 0; j < 8; ++j) v8[j] = fmaxf(v8[j], b2f((ushort_t)c[j]));
        }
        #pragma unroll
        for (int j = 0; j < 8; ++j) {
            v8[j] = fmaxf(v8[j], __shfl_xor(v8[j], 16));
            v8[j] = fmaxf(v8[j], __shfl_xor(v8[j], 32));
        }
        if (lane < 16) {
            #pragma unroll
            for (int j = 0; j < 8; ++j) wpart[w][lane * 8 + j] = v8[j];
        }
    }
    __syncthreads();

    if (t < 128) {
        float m = wpart[0][t];
        #pragma unroll
        for (int ww = 1; ww < 8; ++ww) m = fmaxf(m, wpart[ww][t]);
        float own = fmaxf(fmaxf(smax[0][t], smax[1][t]),
                          fmaxf(smax[2][t], smax[3][t]));
        out[(size_t)bb * 128 + t] = fmaxf(m, own);
    }
}

extern "C" void kernel_launch(void* const* d_in, const int* in_sizes, int n_in,
                              void* d_out, int out_size, void* d_ws, size_t ws_size,
                              hipStream_t stream)
{
    const int*   tokens = (const int*)d_in[0];
    const float* emb    = (const float*)d_in[1];
    const float* Wih    = (const float*)d_in[2];
    const float* Whh    = (const float*)d_in[3];
    const float* bih    = (const float*)d_in[4];
    const float* bhh    = (const float*)d_in[5];
    const float* SW     = (const float*)d_in[6];
    const float* sb     = (const float*)d_in[7];
    const float* cw     = (const float*)d_in[8];
    float* out = (float*)d_out;

    // ws layout
    ushort_t* embb  = (ushort_t*)d_ws;                       // 12.8 MB
    ushort_t* wihb  = embb + (size_t)EMB_N;
    ushort_t* whhb  = wihb + W_N;
    ushort_t* swtb  = whhb + W_N;
    ushort_t* hleaf = swtb + SW_N;                           // 50176*128: 12.85 MB
    float*    sleaf = (float*)(hleaf + (size_t)50176 * 128); // 50176 fp32: 0.2 MB
    ushort_t* h0_3  = (ushort_t*)(sleaf + 50176);            // 64n: 4.2 MB
    ushort_t* pmax  = h0_3 + (size_t)64 * 32768;             // [256][320][128]: 21 MB

    // Weights-only conversion (emb cvt is fused into leafgru)
    cvtw_kernel<<<(CVTW_N / 4 + 255) / 256, 256, 0, stream>>>(
        Wih, Whh, SW, wihb, whhb, swtb);

    // Leaf GRU + leaf attention score, once per vocab entry; converts emb
    // fp32 -> bf16 inline and writes embb as a side effect.
    leafgru_mfma<<<392, 512, 0, stream>>>(
        emb, wihb, bih, bhh, swtb, sb, cw, embb, hleaf, sleaf);

    // L4 merged: leaf blend + GRU + L4 attn + sibling max
    gru_attn_l4<<<512, 512, 0, stream>>>(
        tokens, embb, hleaf, sleaf, wihb, whhb, bih, bhh,
        swtb, sb, cw, h0_3, pmax);

    // L3+L2+L1+root + final max: 256 blocks x 1 batch column
    tail_kernel<<<256, 512, 0, stream>>>(
        tokens, embb, wihb, whhb, bih, bhh, swtb, sb, cw,
        h0_3, pmax, out);
}

// Round 9
// 181.484 us; speedup vs baseline: 1.0200x; 1.0200x over previous
//
#include <hip/hip_runtime.h>
#include <hip/hip_bf16.h>
#include <math.h>

typedef short s8 __attribute__((ext_vector_type(8)));   // 8 bf16 in 4 VGPRs
typedef float f4 __attribute__((ext_vector_type(4)));   // MFMA 16x16 acc
typedef unsigned short ushort_t;

__device__ __forceinline__ float fexp2f(float x) { return __builtin_amdgcn_exp2f(x); }
__device__ __forceinline__ float frcpf(float x)  { return __builtin_amdgcn_rcpf(x); }
__device__ __forceinline__ float sigf(float x) {
    return frcpf(1.f + fexp2f(x * -1.44269504f));
}
__device__ __forceinline__ float tanh_f(float x) {
    float e = fexp2f(x * 2.88539008f);
    return 1.f - 2.f * frcpf(e + 1.f);
}
__device__ __forceinline__ unsigned pk2(float a, float b) {
    __hip_bfloat162 r = __float22bfloat162_rn(make_float2(a, b));
    return *(unsigned*)&r;
}
__device__ __forceinline__ float b2f(ushort_t b) {
    return __uint_as_float(((unsigned)b) << 16);
}

// ---------------------------------------------------------------------------
// Convert emb / Wih / Whh / SW^T to bf16 (packed cvt).
// ---------------------------------------------------------------------------
#define EMB_N   6400000          // 50000*128
#define W_N     49152            // 384*128
#define SW_N    16384            // 128*128
#define CVT_N   (EMB_N + 2 * W_N + SW_N)

__global__ __launch_bounds__(256) void cvt_kernel(
    const float* __restrict__ emb, const float* __restrict__ wih,
    const float* __restrict__ whh, const float* __restrict__ sw,
    ushort_t* __restrict__ embb, ushort_t* __restrict__ wihb,
    ushort_t* __restrict__ whhb, ushort_t* __restrict__ swtb)
{
    int i = (blockIdx.x * 256 + threadIdx.x) * 4;
    if (i >= CVT_N) return;
    if (i < EMB_N) {
        float4 v = *(const float4*)(emb + i);
        uint2 o; o.x = pk2(v.x, v.y); o.y = pk2(v.z, v.w);
        *(uint2*)(embb + i) = o;
    } else if (i < EMB_N + W_N) {
        int j = i - EMB_N;
        float4 v = *(const float4*)(wih + j);
        uint2 o; o.x = pk2(v.x, v.y); o.y = pk2(v.z, v.w);
        *(uint2*)(wihb + j) = o;
    } else if (i < EMB_N + 2 * W_N) {
        int j = i - EMB_N - W_N;
        float4 v = *(const float4*)(whh + j);
        uint2 o; o.x = pk2(v.x, v.y); o.y = pk2(v.z, v.w);
        *(uint2*)(whhb + j) = o;
    } else {
        int j = i - EMB_N - 2 * W_N;
        int f = j >> 7, e0 = j & 127;
        uint2 o;
        o.x = pk2(sw[(e0 + 0) * 128 + f], sw[(e0 + 1) * 128 + f]);
        o.y = pk2(sw[(e0 + 2) * 128 + f], sw[(e0 + 3) * 128 + f]);
        *(uint2*)(swtb + j) = o;         // SWt[f][e]
    }
}

// ---------------------------------------------------------------------------
// Leaf GRU + leaf attention SCORE, both pure functions of the token:
// computed ONCE per vocab entry (50176 padded rows).
// ---------------------------------------------------------------------------
__global__ __launch_bounds__(512, 2) void leafgru_mfma(
    const ushort_t* __restrict__ embb, const ushort_t* __restrict__ wihb,
    const float* __restrict__ bih, const float* __restrict__ bhh,
    const ushort_t* __restrict__ swt, const float* __restrict__ sb,
    const float* __restrict__ cw,
    ushort_t* __restrict__ hleaf, float* __restrict__ sleaf)
{
    __shared__ ushort_t xs[128 * 136];
    __shared__ ushort_t hnew[128 * 136];
    __shared__ float scp[8][128];

    const int t = threadIdx.x;
    const int base = blockIdx.x * 128;       // vocab row base

    {
        int lr = t >> 2, c0 = (t & 3) * 32;
        const ushort_t* src = embb + (size_t)(base + lr) * 128 + c0;
        ushort_t* dst = &xs[lr * 136 + c0];
        #pragma unroll
        for (int i = 0; i < 4; ++i) *(s8*)(dst + 8 * i) = *(const s8*)(src + 8 * i);
    }

    const int lane = t & 63, w = t >> 6;
    const int quad = lane >> 4, l15 = lane & 15;
    const int gA = w * 16 + l15;
    const int g0 = w * 16 + quad * 4;

    s8 bwi[3][4];
    #pragma unroll
    for (int gm = 0; gm < 3; ++gm) {
        const ushort_t* wp = wihb + (size_t)(gm * 128 + gA) * 128 + quad * 8;
        #pragma unroll
        for (int s = 0; s < 4; ++s) bwi[gm][s] = *(const s8*)(wp + 32 * s);
    }
    float bR[4], bZ[4], biN[4], bhN[4];
    {
        float4 a = *(const float4*)(bih + g0);
        float4 b = *(const float4*)(bhh + g0);
        bR[0] = a.x + b.x; bR[1] = a.y + b.y; bR[2] = a.z + b.z; bR[3] = a.w + b.w;
        float4 c = *(const float4*)(bih + 128 + g0);
        float4 d = *(const float4*)(bhh + 128 + g0);
        bZ[0] = c.x + d.x; bZ[1] = c.y + d.y; bZ[2] = c.z + d.z; bZ[3] = c.w + d.w;
        float4 e = *(const float4*)(bih + 256 + g0);
        float4 f = *(const float4*)(bhh + 256 + g0);
        biN[0] = e.x; biN[1] = e.y; biN[2] = e.z; biN[3] = e.w;
        bhN[0] = f.x; bhN[1] = f.y; bhN[2] = f.z; bhN[3] = f.w;
    }

    __syncthreads();

    #pragma unroll 1
    for (int mt = 0; mt < 8; ++mt) {
        const int row = mt * 16 + l15;
        s8 ax[4];
        const ushort_t* ap = &xs[row * 136 + quad * 8];
        #pragma unroll
        for (int s = 0; s < 4; ++s) ax[s] = *(const s8*)(ap + 32 * s);

        f4 accR = (f4)0.f, accZ = (f4)0.f, accN = (f4)0.f;
        #pragma unroll
        for (int s = 0; s < 4; ++s) {
            accR = __builtin_amdgcn_mfma_f32_16x16x32_bf16(bwi[0][s], ax[s], accR, 0, 0, 0);
            accZ = __builtin_amdgcn_mfma_f32_16x16x32_bf16(bwi[1][s], ax[s], accZ, 0, 0, 0);
            accN = __builtin_amdgcn_mfma_f32_16x16x32_bf16(bwi[2][s], ax[s], accN, 0, 0, 0);
        }
        float hv[4];
        #pragma unroll
        for (int r = 0; r < 4; ++r) {
            // leaf GRU (h0=0), 5 transcendentals:
            // h = tanh(an)*(1-sig(aZ)) = (E-1)*F / ((E+1)*(1+F))
            float G = fexp2f((accR[r] + bR[r]) * -1.44269504f);
            float rr = frcpf(1.f + G);
            float an = accN[r] + biN[r] + rr * bhN[r];
            float E = fexp2f(an * 2.88539008f);
            float F = fexp2f((accZ[r] + bZ[r]) * -1.44269504f);
            float d = frcpf((E + 1.f) * (1.f + F));
            hv[r] = (E - 1.f) * F * d;
        }
        uint2 ov; ov.x = pk2(hv[0], hv[1]); ov.y = pk2(hv[2], hv[3]);
        *(uint2*)&hnew[row * 136 + g0] = ov;
        *(uint2*)(hleaf + (size_t)(base + row) * 128 + g0) = ov;
    }
    __syncthreads();

    // ---- attention score per vocab row ----
    s8 bsw[4];
    {
        const ushort_t* wp = swt + (size_t)gA * 128 + quad * 8;
        #pragma unroll
        for (int s = 0; s < 4; ++s) bsw[s] = *(const s8*)(wp + 32 * s);
    }
    float sb4[4], cw4[4];
    {
        float4 a = *(const float4*)(sb + g0);
        float4 b = *(const float4*)(cw + g0);
        sb4[0] = a.x; sb4[1] = a.y; sb4[2] = a.z; sb4[3] = a.w;
        cw4[0] = b.x; cw4[1] = b.y; cw4[2] = b.z; cw4[3] = b.w;
    }

    #pragma unroll 1
    for (int mt = 0; mt < 8; ++mt) {
        const int crow = mt * 16 + l15;
        s8 a[4];
        const ushort_t* ap = &hnew[crow * 136 + quad * 8];
        #pragma unroll
        for (int s = 0; s < 4; ++s) a[s] = *(const s8*)(ap + 32 * s);

        f4 acc = (f4)0.f;
        #pragma unroll
        for (int s = 0; s < 4; ++s)
            acc = __builtin_amdgcn_mfma_f32_16x16x32_bf16(bsw[s], a[s], acc, 0, 0, 0);

        float part = 0.f;
        #pragma unroll
        for (int r = 0; r < 4; ++r)
            part += tanh_f(acc[r] + sb4[r]) * cw4[r];
        part += __shfl_xor(part, 16);
        part += __shfl_xor(part, 32);
        if (quad == 0) scp[w][crow] = part;
    }
    __syncthreads();

    if (t < 128) {
        float s = 0.f;
        #pragma unroll
        for (int ww = 0; ww < 8; ++ww) s += scp[ww][t];
        sleaf[base + t] = tanh_f(s);
    }
}

// ---------------------------------------------------------------------------
// MERGED L4 kernel: leaf-blend h0 (pipelined quarters) + GRU MFMA + L4
// attention + sibling-max, all in one block. Block = (L3 parent p, 32-batch
// tile): 128 rows = 4 sibling L4 nodes x 32 batch. Quarter q == sibling node
// 4p+q. After quarter q's MFMA the GRU output h is written back into the
// DEAD xs rows (held in regs across the barrier); attnmax runs in-place.
// ---------------------------------------------------------------------------
__global__ __launch_bounds__(512, 2) void gru_attn_l4(
    const int* __restrict__ tokens, const ushort_t* __restrict__ embb,
    const ushort_t* __restrict__ hleaf, const float* __restrict__ sleaf,
    const ushort_t* __restrict__ wihb, const ushort_t* __restrict__ whhb,
    const float* __restrict__ bih, const float* __restrict__ bhh,
    const ushort_t* __restrict__ swt, const float* __restrict__ sb,
    const float* __restrict__ cw,
    ushort_t* __restrict__ h0out, ushort_t* __restrict__ pmaxs)
{
    __shared__ ushort_t xs[128 * 136];     // emb x -> (after GRU) h
    __shared__ ushort_t hs[128 * 136];     // h0 (leaf-attn blend)
    __shared__ float scp[8][128];
    __shared__ float sc[128];
    __shared__ float al[4][32];

    const int t = threadIdx.x;
    const int p  = blockIdx.x >> 3;          // L3 parent 0..63
    const int b0 = (blockIdx.x & 7) * 32;    // batch tile

    const int lane = t & 63, w = t >> 6;
    const int quad = lane >> 4, l15 = lane & 15;
    const int gA = w * 16 + l15;
    const int g0 = w * 16 + quad * 4;

    // staging geometry: 16 thr/row, 16 B (8 shorts) per thread
    const int slr = t >> 4;                  // row-in-quarter 0..31
    const int sc0 = (t & 15) * 8;            // col offset (shorts)

    // ---- weights & biases ----
    s8 bwi[3][4], bwh[3][4];
    #pragma unroll
    for (int gm = 0; gm < 3; ++gm) {
        const ushort_t* wp = wihb + (size_t)(gm * 128 + gA) * 128 + quad * 8;
        #pragma unroll
        for (int s = 0; s < 4; ++s) bwi[gm][s] = *(const s8*)(wp + 32 * s);
        const ushort_t* wp2 = whhb + (size_t)(gm * 128 + gA) * 128 + quad * 8;
        #pragma unroll
        for (int s = 0; s < 4; ++s) bwh[gm][s] = *(const s8*)(wp2 + 32 * s);
    }
    float bR[4], bZ[4], biN[4], bhN[4];
    {
        float4 a = *(const float4*)(bih + g0);
        float4 b = *(const float4*)(bhh + g0);
        bR[0] = a.x + b.x; bR[1] = a.y + b.y; bR[2] = a.z + b.z; bR[3] = a.w + b.w;
        float4 c = *(const float4*)(bih + 128 + g0);
        float4 d = *(const float4*)(bhh + 128 + g0);
        bZ[0] = c.x + d.x; bZ[1] = c.y + d.y; bZ[2] = c.z + d.z; bZ[3] = c.w + d.w;
        float4 e = *(const float4*)(bih + 256 + g0);
        float4 f = *(const float4*)(bhh + 256 + g0);
        biN[0] = e.x; biN[1] = e.y; biN[2] = e.z; biN[3] = e.w;
        bhN[0] = f.x; bhN[1] = f.y; bhN[2] = f.z; bhN[3] = f.w;
    }

    // ---- pipeline registers for the staged quarter ----
    s8 pv0, pv1, pv2, pv3, pxv;
    float ps0, ps1, ps2, ps3;
    int pnode, pb;

#define STAGE_LOAD(Q) {                                                     \
        int lr_ = (Q) * 32 + slr;                                           \
        pnode = 4 * p + (lr_ >> 5); pb = b0 + (lr_ & 31);                   \
        int lt0 = tokens[(341 + 4 * pnode + 0) * 256 + pb];                 \
        int lt1 = tokens[(341 + 4 * pnode + 1) * 256 + pb];                 \
        int lt2 = tokens[(341 + 4 * pnode + 2) * 256 + pb];                 \
        int lt3 = tokens[(341 + 4 * pnode + 3) * 256 + pb];                 \
        pv0 = *(const s8*)(hleaf + (size_t)lt0 * 128 + sc0);                \
        pv1 = *(const s8*)(hleaf + (size_t)lt1 * 128 + sc0);                \
        pv2 = *(const s8*)(hleaf + (size_t)lt2 * 128 + sc0);                \
        pv3 = *(const s8*)(hleaf + (size_t)lt3 * 128 + sc0);                \
        ps0 = sleaf[lt0]; ps1 = sleaf[lt1]; ps2 = sleaf[lt2]; ps3 = sleaf[lt3]; \
        int tok_ = tokens[(85 + pnode) * 256 + pb];                         \
        pxv = *(const s8*)(embb + (size_t)tok_ * 128 + sc0);                \
    }

#define STAGE_FIN(Q) {                                                      \
        int lr_ = (Q) * 32 + slr;                                           \
        float m_ = fmaxf(fmaxf(ps0, ps1), fmaxf(ps2, ps3));                 \
        float e0_ = fexp2f((ps0 - m_) * 1.44269504f);                       \
        float e1_ = fexp2f((ps1 - m_) * 1.44269504f);                       \
        float e2_ = fexp2f((ps2 - m_) * 1.44269504f);                       \
        float e3_ = fexp2f((ps3 - m_) * 1.44269504f);                       \
        float inv_ = frcpf(e0_ + e1_ + e2_ + e3_);                          \
        float a0_ = e0_ * inv_, a1_ = e1_ * inv_;                           \
        float a2_ = e2_ * inv_, a3_ = e3_ * inv_;                           \
        float o_[8], mm_[8];                                                \
        _Pragma("unroll")                                                   \
        for (int j = 0; j < 8; ++j) {                                       \
            float y0 = b2f((ushort_t)pv0[j]), y1 = b2f((ushort_t)pv1[j]);   \
            float y2 = b2f((ushort_t)pv2[j]), y3 = b2f((ushort_t)pv3[j]);   \
            o_[j]  = a0_ * y0 + a1_ * y1 + a2_ * y2 + a3_ * y3;             \
            mm_[j] = fmaxf(fmaxf(y0, y1), fmaxf(y2, y3));                   \
        }                                                                   \
        uint4 ovv_, mvv_;                                                   \
        ovv_.x = pk2(o_[0], o_[1]);  ovv_.y = pk2(o_[2], o_[3]);            \
        ovv_.z = pk2(o_[4], o_[5]);  ovv_.w = pk2(o_[6], o_[7]);            \
        mvv_.x = pk2(mm_[0], mm_[1]); mvv_.y = pk2(mm_[2], mm_[3]);         \
        mvv_.z = pk2(mm_[4], mm_[5]); mvv_.w = pk2(mm_[6], mm_[7]);         \
        *(uint4*)&hs[lr_ * 136 + sc0] = ovv_;                               \
        *(s8*)&xs[lr_ * 136 + sc0] = pxv;                                   \
        *(uint4*)(pmaxs + ((size_t)pb * 320 + pnode) * 128 + sc0) = mvv_;   \
    }

    // ---- prologue: stage quarter 0 ----
    STAGE_LOAD(0);
    STAGE_FIN(0);
    __syncthreads();

    uint2 ph[2];                            // h output held across barrier

    #pragma unroll 1
    for (int q = 0; q < 4; ++q) {
        if (q < 3) STAGE_LOAD(q + 1);      // issue next quarter's gathers

        // ---- MFMA for quarter q: rows q*32 .. q*32+31 (mt = 2q, 2q+1) ----
        #pragma unroll 1
        for (int mq = 0; mq < 2; ++mq) {
            const int mt = q * 2 + mq;
            const int row = mt * 16 + l15;
            s8 ax[4], ah[4];
            {
                const ushort_t* ap = &xs[row * 136 + quad * 8];
                #pragma unroll
                for (int s = 0; s < 4; ++s) ax[s] = *(const s8*)(ap + 32 * s);
                const ushort_t* hp = &hs[row * 136 + quad * 8];
                #pragma unroll
                for (int s = 0; s < 4; ++s) ah[s] = *(const s8*)(hp + 32 * s);
            }

            f4 accR = (f4)0.f, accZ = (f4)0.f, accN = (f4)0.f, accNh = (f4)0.f;
            #pragma unroll
            for (int s = 0; s < 4; ++s) {
                accR = __builtin_amdgcn_mfma_f32_16x16x32_bf16(bwi[0][s], ax[s], accR, 0, 0, 0);
                accZ = __builtin_amdgcn_mfma_f32_16x16x32_bf16(bwi[1][s], ax[s], accZ, 0, 0, 0);
                accN = __builtin_amdgcn_mfma_f32_16x16x32_bf16(bwi[2][s], ax[s], accN, 0, 0, 0);
            }
            #pragma unroll
            for (int s = 0; s < 4; ++s) {
                accR  = __builtin_amdgcn_mfma_f32_16x16x32_bf16(bwh[0][s], ah[s], accR, 0, 0, 0);
                accZ  = __builtin_amdgcn_mfma_f32_16x16x32_bf16(bwh[1][s], ah[s], accZ, 0, 0, 0);
                accNh = __builtin_amdgcn_mfma_f32_16x16x32_bf16(bwh[2][s], ah[s], accNh, 0, 0, 0);
            }

            float h0v[4];
            {
                short4 h04 = *(const short4*)&hs[row * 136 + g0];
                h0v[0] = b2f((ushort_t)h04.x); h0v[1] = b2f((ushort_t)h04.y);
                h0v[2] = b2f((ushort_t)h04.z); h0v[3] = b2f((ushort_t)h04.w);
            }
            float hv[4];
            #pragma unroll
            for (int r = 0; r < 4; ++r) {
                // h = (nn*(1-z) + z*h0) = ((E-1)*F + h0*(E+1)) / ((E+1)*(1+F))
                float G = fexp2f((accR[r] + bR[r]) * -1.44269504f);
                float rr = frcpf(1.f + G);
                float an = accN[r] + biN[r] + rr * (accNh[r] + bhN[r]);
                float E = fexp2f(an * 2.88539008f);
                float F = fexp2f((accZ[r] + bZ[r]) * -1.44269504f);
                float d = frcpf((E + 1.f) * (1.f + F));
                hv[r] = ((E - 1.f) * F + h0v[r] * (E + 1.f)) * d;
            }
            uint2 ov; ov.x = pk2(hv[0], hv[1]); ov.y = pk2(hv[2], hv[3]);
            ph[mq] = ov;
        }

        if (q < 3) STAGE_FIN(q + 1);       // wait gathers, blend, LDS write
        __syncthreads();

        // ---- write quarter q's h into its now-dead xs rows ----
        #pragma unroll
        for (int mq = 0; mq < 2; ++mq) {
            const int row = (q * 2 + mq) * 16 + l15;
            *(uint2*)&xs[row * 136 + g0] = ph[mq];
        }
    }
#undef STAGE_LOAD
#undef STAGE_FIN

    __syncthreads();                        // all h rows visible in xs

    // ================= L4 attention + sibling max (in-place) =================
    s8 bsw[4];
    {
        const ushort_t* wp = swt + (size_t)gA * 128 + quad * 8;
        #pragma unroll
        for (int s = 0; s < 4; ++s) bsw[s] = *(const s8*)(wp + 32 * s);
    }
    float sb4[4], cw4[4];
    {
        float4 a = *(const float4*)(sb + g0);
        float4 b = *(const float4*)(cw + g0);
        sb4[0] = a.x; sb4[1] = a.y; sb4[2] = a.z; sb4[3] = a.w;
        cw4[0] = b.x; cw4[1] = b.y; cw4[2] = b.z; cw4[3] = b.w;
    }

    #pragma unroll 1
    for (int mt = 0; mt < 8; ++mt) {
        const int crow = mt * 16 + l15;
        s8 a[4];
        const ushort_t* ap = &xs[crow * 136 + quad * 8];
        #pragma unroll
        for (int s = 0; s < 4; ++s) a[s] = *(const s8*)(ap + 32 * s);

        f4 acc = (f4)0.f;
        #pragma unroll
        for (int s = 0; s < 4; ++s)
            acc = __builtin_amdgcn_mfma_f32_16x16x32_bf16(bsw[s], a[s], acc, 0, 0, 0);

        float part = 0.f;
        #pragma unroll
        for (int r = 0; r < 4; ++r)
            part += tanh_f(acc[r] + sb4[r]) * cw4[r];
        part += __shfl_xor(part, 16);
        part += __shfl_xor(part, 32);
        if (quad == 0) scp[w][crow] = part;
    }
    __syncthreads();

    if (t < 128) {
        float s = 0.f;
        #pragma unroll
        for (int ww = 0; ww < 8; ++ww) s += scp[ww][t];
        sc[t] = tanh_f(s);
    }
    __syncthreads();

    if (t < 32) {
        float s0 = sc[t], s1 = sc[32 + t], s2 = sc[64 + t], s3 = sc[96 + t];
        float m = fmaxf(fmaxf(s0, s1), fmaxf(s2, s3));
        float e0 = fexp2f((s0 - m) * 1.44269504f), e1 = fexp2f((s1 - m) * 1.44269504f);
        float e2 = fexp2f((s2 - m) * 1.44269504f), e3 = fexp2f((s3 - m) * 1.44269504f);
        float inv = frcpf(e0 + e1 + e2 + e3);
        al[0][t] = e0 * inv; al[1][t] = e1 * inv; al[2][t] = e2 * inv; al[3][t] = e3 * inv;
    }
    __syncthreads();

    {
        int bl = t >> 4, e0 = (t & 15) * 8;
        float a0 = al[0][bl], a1 = al[1][bl], a2 = al[2][bl], a3 = al[3][bl];
        s8 c0v = *(const s8*)&xs[(0 * 32 + bl) * 136 + e0];
        s8 c1v = *(const s8*)&xs[(1 * 32 + bl) * 136 + e0];
        s8 c2v = *(const s8*)&xs[(2 * 32 + bl) * 136 + e0];
        s8 c3v = *(const s8*)&xs[(3 * 32 + bl) * 136 + e0];
        float o[8], m[8];
        #pragma unroll
        for (int j = 0; j < 8; ++j) {
            float x0 = b2f((ushort_t)c0v[j]), x1 = b2f((ushort_t)c1v[j]);
            float x2 = b2f((ushort_t)c2v[j]), x3 = b2f((ushort_t)c3v[j]);
            o[j] = a0 * x0 + a1 * x1 + a2 * x2 + a3 * x3;
            m[j] = fmaxf(fmaxf(x0, x1), fmaxf(x2, x3));
        }
        uint4 ovv, mvv;
        ovv.x = pk2(o[0], o[1]); ovv.y = pk2(o[2], o[3]);
        ovv.z = pk2(o[4], o[5]); ovv.w = pk2(o[6], o[7]);
        mvv.x = pk2(m[0], m[1]); mvv.y = pk2(m[2], m[3]);
        mvv.z = pk2(m[4], m[5]); mvv.w = pk2(m[6], m[7]);
        // h0_3: [node][batch][col]
        size_t rh = ((size_t)p * 256 + b0 + bl) * 128 + e0;
        *(uint4*)(h0out + rh) = ovv;
        // pmax: [batch][slot][col], L4 slots start at 256
        size_t rp = ((size_t)(b0 + bl) * 320 + 256 + p) * 128 + e0;
        *(uint4*)(pmaxs + rp) = mvv;
    }
}

// ---------------------------------------------------------------------------
// TAIL kernel: L3/L2/L1/root + final max. 256 blocks x 1 batch column.
// ---------------------------------------------------------------------------
__global__ __launch_bounds__(512, 1) void tail_kernel(
    const int* __restrict__ tokens, const ushort_t* __restrict__ embb,
    const ushort_t* __restrict__ wihb, const ushort_t* __restrict__ whhb,
    const float* __restrict__ bih, const float* __restrict__ bhh,
    const ushort_t* __restrict__ swt, const float* __restrict__ sb,
    const float* __restrict__ cw,
    const ushort_t* __restrict__ h0g,      // h0 for L3 (64 nodes, [n][b][c])
    const ushort_t* __restrict__ pmax,     // [batch][320][128]
    float* __restrict__ out)
{
    __shared__ ushort_t xs[64 * 136];
    __shared__ ushort_t hnew[64 * 136];
    __shared__ ushort_t hs[64 * 136];      // h0: staged (L3), attn-written after
    __shared__ float scp[8][64];
    __shared__ float sc[64];
    __shared__ float al[4][16];
    __shared__ float smax[4][128];
    __shared__ float wpart[8][128];

    const int t = threadIdx.x;
    const int bb = blockIdx.x;             // one batch column
    const int lane = t & 63, w = t >> 6;
    const int quad = lane >> 4, l15 = lane & 15;
    const int gA = w * 16 + l15;
    const int g0 = w * 16 + quad * 4;

    s8 bwi[3][4], bwh[3][4];
    #pragma unroll
    for (int gm = 0; gm < 3; ++gm) {
        const ushort_t* wp = wihb + (size_t)(gm * 128 + gA) * 128 + quad * 8;
        #pragma unroll
        for (int s = 0; s < 4; ++s) bwi[gm][s] = *(const s8*)(wp + 32 * s);
        const ushort_t* wp2 = whhb + (size_t)(gm * 128 + gA) * 128 + quad * 8;
        #pragma unroll
        for (int s = 0; s < 4; ++s) bwh[gm][s] = *(const s8*)(wp2 + 32 * s);
    }
    float bR[4], bZ[4], biN[4], bhN[4];
    {
        float4 a = *(const float4*)(bih + g0);
        float4 b = *(const float4*)(bhh + g0);
        bR[0] = a.x + b.x; bR[1] = a.y + b.y; bR[2] = a.z + b.z; bR[3] = a.w + b.w;
        float4 c = *(const float4*)(bih + 128 + g0);
        float4 d = *(const float4*)(bhh + 128 + g0);
        bZ[0] = c.x + d.x; bZ[1] = c.y + d.y; bZ[2] = c.z + d.z; bZ[3] = c.w + d.w;
        float4 e = *(const float4*)(bih + 256 + g0);
        float4 f = *(const float4*)(bhh + 256 + g0);
        biN[0] = e.x; biN[1] = e.y; biN[2] = e.z; biN[3] = e.w;
        bhN[0] = f.x; bhN[1] = f.y; bhN[2] = f.z; bhN[3] = f.w;
    }
    s8 bsw[4];
    {
        const ushort_t* wp = swt + (size_t)gA * 128 + quad * 8;
        #pragma unroll
        for (int s = 0; s < 4; ++s) bsw[s] = *(const s8*)(wp + 32 * s);
    }
    float sb4[4], cw4[4];
    {
        float4 a = *(const float4*)(sb + g0);
        float4 b = *(const float4*)(cw + g0);
        sb4[0] = a.x; sb4[1] = a.y; sb4[2] = a.z; sb4[3] = a.w;
        cw4[0] = b.x; cw4[1] = b.y; cw4[2] = b.z; cw4[3] = b.w;
    }

    float vmax = -INFINITY;

    const int nodesA[4] = {64, 16, 4, 1};
    const int tok0A[4]  = {21, 5, 1, 0};

    #pragma unroll 1
    for (int L = 0; L < 4; ++L) {
        const int nodes = nodesA[L], tok0 = tok0A[L];
        const int R = (nodes < 16) ? 16 : nodes;   // 64,16,16,16
        const int mts = R >> 4;

        // ---- stage x (+h0 from global for L3): 8 thr/row, 16 shorts ----
        {
            int lr = t >> 3, c0 = (t & 7) * 16;
            if (lr < R) {
                int n = min(lr, nodes - 1);        // clamp -> dup pad rows
                int tok = tokens[(tok0 + n) * 256 + bb];
                const ushort_t* src = embb + (size_t)tok * 128 + c0;
                ushort_t* dst = &xs[lr * 136 + c0];
                *(s8*)(dst)     = *(const s8*)(src);
                *(s8*)(dst + 8) = *(const s8*)(src + 8);
                if (L == 0) {
                    const ushort_t* hsrc = h0g + ((size_t)n * 256 + bb) * 128 + c0;
                    ushort_t* hdst = &hs[lr * 136 + c0];
                    *(s8*)(hdst)     = *(const s8*)(hsrc);
                    *(s8*)(hdst + 8) = *(const s8*)(hsrc + 8);
                }
            }
        }
        __syncthreads();

        // ---- GRU ----
        for (int mt = 0; mt < mts; ++mt) {
            const int row = mt * 16 + l15;
            const int hr = min(row, nodes - 1);    // clamped h0 row
            s8 ax[4], ah[4];
            {
                const ushort_t* ap = &xs[row * 136 + quad * 8];
                #pragma unroll
                for (int s = 0; s < 4; ++s) ax[s] = *(const s8*)(ap + 32 * s);
                const ushort_t* hp = &hs[hr * 136 + quad * 8];
                #pragma unroll
                for (int s = 0; s < 4; ++s) ah[s] = *(const s8*)(hp + 32 * s);
            }
            f4 accR = (f4)0.f, accZ = (f4)0.f, accN = (f4)0.f, accNh = (f4)0.f;
            #pragma unroll
            for (int s = 0; s < 4; ++s) {
                accR = __builtin_amdgcn_mfma_f32_16x16x32_bf16(bwi[0][s], ax[s], accR, 0, 0, 0);
                accZ = __builtin_amdgcn_mfma_f32_16x16x32_bf16(bwi[1][s], ax[s], accZ, 0, 0, 0);
                accN = __builtin_amdgcn_mfma_f32_16x16x32_bf16(bwi[2][s], ax[s], accN, 0, 0, 0);
            }
            #pragma unroll
            for (int s = 0; s < 4; ++s) {
                accR  = __builtin_amdgcn_mfma_f32_16x16x32_bf16(bwh[0][s], ah[s], accR, 0, 0, 0);
                accZ  = __builtin_amdgcn_mfma_f32_16x16x32_bf16(bwh[1][s], ah[s], accZ, 0, 0, 0);
                accNh = __builtin_amdgcn_mfma_f32_16x16x32_bf16(bwh[2][s], ah[s], accNh, 0, 0, 0);
            }
            float h0v[4];
            {
                short4 h04 = *(const short4*)&hs[hr * 136 + g0];
                h0v[0] = b2f((ushort_t)h04.x); h0v[1] = b2f((ushort_t)h04.y);
                h0v[2] = b2f((ushort_t)h04.z); h0v[3] = b2f((ushort_t)h04.w);
            }
            float hv[4];
            #pragma unroll
            for (int r = 0; r < 4; ++r) {
                float rr = sigf(accR[r] + bR[r]);
                float zz = sigf(accZ[r] + bZ[r]);
                float nn = tanh_f(accN[r] + biN[r] + rr * (accNh[r] + bhN[r]));
                hv[r] = nn + zz * (h0v[r] - nn);
            }
            uint2 ov; ov.x = pk2(hv[0], hv[1]); ov.y = pk2(hv[2], hv[3]);
            *(uint2*)&hnew[row * 136 + g0] = ov;
        }
        __syncthreads();

        // ---- running max (pad rows are dups of real rows -> harmless) ----
        {
            int col = t & 127, g = t >> 7;
            for (int r = g; r < R; r += 4)
                vmax = fmaxf(vmax, b2f(hnew[r * 136 + col]));
        }

        if (L < 3) {
            // ---- attention scores ----
            for (int mt = 0; mt < mts; ++mt) {
                const int crow = mt * 16 + l15;
                s8 a[4];
                const ushort_t* ap = &hnew[crow * 136 + quad * 8];
                #pragma unroll
                for (int s = 0; s < 4; ++s) a[s] = *(const s8*)(ap + 32 * s);
                f4 acc = (f4)0.f;
                #pragma unroll
                for (int s = 0; s < 4; ++s)
                    acc = __builtin_amdgcn_mfma_f32_16x16x32_bf16(bsw[s], a[s], acc, 0, 0, 0);
                float part = 0.f;
                #pragma unroll
                for (int r = 0; r < 4; ++r)
                    part += tanh_f(acc[r] + sb4[r]) * cw4[r];
                part += __shfl_xor(part, 16);
                part += __shfl_xor(part, 32);
                if (quad == 0) scp[w][crow] = part;
            }
            __syncthreads();
            if (t < R) {
                float s = 0.f;
                #pragma unroll
                for (int g = 0; g < 8; ++g) s += scp[g][t];
                sc[t] = tanh_f(s);
            }
            __syncthreads();
            const int P = nodes >> 2;              // parents: 16, 4, 1
            if (t < P) {
                float s0 = sc[4 * t + 0], s1 = sc[4 * t + 1];
                float s2 = sc[4 * t + 2], s3 = sc[4 * t + 3];
                float m = fmaxf(fmaxf(s0, s1), fmaxf(s2, s3));
                float e0 = fexp2f((s0 - m) * 1.44269504f);
                float e1 = fexp2f((s1 - m) * 1.44269504f);
                float e2 = fexp2f((s2 - m) * 1.44269504f);
                float e3 = fexp2f((s3 - m) * 1.44269504f);
                float inv = frcpf(e0 + e1 + e2 + e3);
                al[0][t] = e0 * inv; al[1][t] = e1 * inv;
                al[2][t] = e2 * inv; al[3][t] = e3 * inv;
            }
            __syncthreads();
            if (t < 16 * P) {
                int bl = t >> 4, e0 = (t & 15) * 8;
                float a0 = al[0][bl], a1 = al[1][bl], a2 = al[2][bl], a3 = al[3][bl];
                s8 c0v = *(const s8*)&hnew[(4 * bl + 0) * 136 + e0];
                s8 c1v = *(const s8*)&hnew[(4 * bl + 1) * 136 + e0];
                s8 c2v = *(const s8*)&hnew[(4 * bl + 2) * 136 + e0];
                s8 c3v = *(const s8*)&hnew[(4 * bl + 3) * 136 + e0];
                float o[8];
                #pragma unroll
                for (int j = 0; j < 8; ++j) {
                    o[j] = a0 * b2f((ushort_t)c0v[j]) + a1 * b2f((ushort_t)c1v[j])
                         + a2 * b2f((ushort_t)c2v[j]) + a3 * b2f((ushort_t)c3v[j]);
                }
                uint4 ovv;
                ovv.x = pk2(o[0], o[1]); ovv.y = pk2(o[2], o[3]);
                ovv.z = pk2(o[4], o[5]); ovv.w = pk2(o[6], o[7]);
                *(uint4*)&hs[bl * 136 + e0] = ovv;   // parent h0 -> hs row bl
            }
            __syncthreads();
        }
    }

    // ---- own-level max -> LDS ----
    smax[t >> 7][t & 127] = vmax;

    // ---- final reduce over 320 pmax slots (contiguous per batch row) ----
    {
        int cg = t & 15;              // col group (8 cols) == lane & 15
        int ck = t >> 4;              // slot chunk 0..31
        const ushort_t* base = pmax + (size_t)bb * 320 * 128 + cg * 8;
        float v8[8];
        #pragma unroll
        for (int j = 0; j < 8; ++j) v8[j] = -INFINITY;
        for (int s = ck; s < 320; s += 32) {
            s8 c = *(const s8*)(base + (size_t)s * 128);
            #pragma unroll
            for (int j = 0; j < 8; ++j) v8[j] = fmaxf(v8[j], b2f((ushort_t)c[j]));
        }
        #pragma unroll
        for (int j = 0; j < 8; ++j) {
            v8[j] = fmaxf(v8[j], __shfl_xor(v8[j], 16));
            v8[j] = fmaxf(v8[j], __shfl_xor(v8[j], 32));
        }
        if (lane < 16) {
            #pragma unroll
            for (int j = 0; j < 8; ++j) wpart[w][lane * 8 + j] = v8[j];
        }
    }
    __syncthreads();

    if (t < 128) {
        float m = wpart[0][t];
        #pragma unroll
        for (int ww = 1; ww < 8; ++ww) m = fmaxf(m, wpart[ww][t]);
        float own = fmaxf(fmaxf(smax[0][t], smax[1][t]),
                          fmaxf(smax[2][t], smax[3][t]));
        out[(size_t)bb * 128 + t] = fmaxf(m, own);
    }
}

extern "C" void kernel_launch(void* const* d_in, const int* in_sizes, int n_in,
                              void* d_out, int out_size, void* d_ws, size_t ws_size,
                              hipStream_t stream)
{
    const int*   tokens = (const int*)d_in[0];
    const float* emb    = (const float*)d_in[1];
    const float* Wih    = (const float*)d_in[2];
    const float* Whh    = (const float*)d_in[3];
    const float* bih    = (const float*)d_in[4];
    const float* bhh    = (const float*)d_in[5];
    const float* SW     = (const float*)d_in[6];
    const float* sb     = (const float*)d_in[7];
    const float* cw     = (const float*)d_in[8];
    float* out = (float*)d_out;

    // ws layout
    ushort_t* embb  = (ushort_t*)d_ws;                       // 12.8 MB
    ushort_t* wihb  = embb + (size_t)EMB_N;
    ushort_t* whhb  = wihb + W_N;
    ushort_t* swtb  = whhb + W_N;
    ushort_t* hleaf = swtb + SW_N;                           // 50176*128: 12.85 MB
    float*    sleaf = (float*)(hleaf + (size_t)50176 * 128); // 50176 fp32: 0.2 MB
    ushort_t* h0_3  = (ushort_t*)(sleaf + 50176);            // 64n: 4.2 MB
    ushort_t* pmax  = h0_3 + (size_t)64 * 32768;             // [256][320][128]: 21 MB

    cvt_kernel<<<(CVT_N / 4 + 255) / 256, 256, 0, stream>>>(
        emb, Wih, Whh, SW, embb, wihb, whhb, swtb);

    // Leaf GRU + leaf attention score, once per vocab entry
    leafgru_mfma<<<392, 512, 0, stream>>>(
        embb, wihb, bih, bhh, swtb, sb, cw, hleaf, sleaf);

    // L4 merged: leaf blend + GRU + L4 attn + sibling max (no h4 round-trip)
    gru_attn_l4<<<512, 512, 0, stream>>>(
        tokens, embb, hleaf, sleaf, wihb, whhb, bih, bhh,
        swtb, sb, cw, h0_3, pmax);

    // L3+L2+L1+root + final max: 256 blocks x 1 batch column
    tail_kernel<<<256, 512, 0, stream>>>(
        tokens, embb, wihb, whhb, bih, bhh, swtb, sb, cw,
        h0_3, pmax, out);
}